// Round 4
// baseline (606.238 us; speedup 1.0000x reference)
//
#include <hip/hip_runtime.h>

#define N_NODES 100000
#define N_EDGES 1600000
#define N_GRAPHS 256
#define HID 128
#define BN_EPS 1e-5f

#define NT 1563        // ceil(N_NODES/64) tile buckets
#define EB 4096        // edges per reorder block
#define RB 391         // ceil(N_EDGES/EB)
#define MB 1563        // mlp blocks

typedef __bf16 bf16x8 __attribute__((ext_vector_type(8)));
typedef __bf16 bf16x4 __attribute__((ext_vector_type(4)));
typedef __bf16 bf16x2 __attribute__((ext_vector_type(2)));
typedef float f32x4 __attribute__((ext_vector_type(4)));

// ---------------- fused setup: x->bf16, weight prep, per-graph counts -------
__global__ __launch_bounds__(256) void setup_kernel(
    const float* __restrict__ x, __bf16* __restrict__ xb,
    const float* __restrict__ wa, const float* __restrict__ wb,
    const float* __restrict__ wc, const float* __restrict__ wd,
    const float* __restrict__ we, const float* __restrict__ wf,
    __bf16* __restrict__ wt,
    const int* __restrict__ batch, int* __restrict__ counts) {
  int b = blockIdx.x;
  if (b < 6250) {  // x convert: chunks of 4 floats
    int idx = b * 256 + threadIdx.x;
    if (idx >= N_NODES * 16) return;
    f32x4 v = ((const f32x4*)x)[idx];
    bf16x4 o = {(__bf16)v[0], (__bf16)v[1], (__bf16)v[2], (__bf16)v[3]};
    ((bf16x4*)xb)[idx] = o;
  } else if (b < 6250 + 352) {  // weight prep
    int idx = (b - 6250) * 256 + threadIdx.x;
    if (idx >= 90112) return;
    const float* w;
    int K, local;
    if (idx < 8192) { w = wa; K = 64; local = idx; }
    else {
      int s = (idx - 8192) / 16384;
      local = (idx - 8192) - s * 16384;
      K = 128;
      w = (s == 0) ? wb : (s == 1) ? wc : (s == 2) ? wd : (s == 3) ? we : wf;
    }
    int n = local / K, k = local - n * K;
    wt[idx] = (__bf16)w[k * 128 + n];
  } else {  // per-graph node counts (batch is sorted)
    int t = (b - 6602) * 256 + threadIdx.x;
    int r0 = t * 64;
    if (r0 >= N_NODES) return;
    int rend = min(r0 + 64, N_NODES);
    int curg = batch[r0], cnt = 0;
    for (int r = r0; r < rend; r++) {
      int g = batch[r];
      if (g != curg) {
        atomicAdd(&counts[curg], cnt);
        curg = g;
        cnt = 1;
      } else {
        cnt++;
      }
    }
    atomicAdd(&counts[curg], cnt);
  }
}

// ---------------- CSR stage 1: tile-bucket histogram (LDS-staged) -----------
__global__ __launch_bounds__(256) void tile_hist_kernel(const int* __restrict__ ei,
                                                        int* __restrict__ tcnt) {
  __shared__ int hist[NT];
  int t = threadIdx.x;
  for (int i = t; i < NT; i += 256) hist[i] = 0;
  __syncthreads();
  int base = blockIdx.x * EB;
#pragma unroll 4
  for (int i = 0; i < EB / 256; i++) {
    int e = base + i * 256 + t;
    if (e < N_EDGES) atomicAdd(&hist[ei[N_EDGES + e] >> 6], 1);
  }
  __syncthreads();
  for (int i = t; i < NT; i += 256) {
    int h = hist[i];
    if (h) atomicAdd(&tcnt[i], h);
  }
}

// ---------------- CSR stage 2: scan 1563 tile counts ------------------------
__global__ __launch_bounds__(256) void tile_scan_kernel(const int* __restrict__ tcnt,
                                                        int* __restrict__ tstart,
                                                        int* __restrict__ gcursor) {
  __shared__ int ps[256];
  int t = threadIdx.x;
  const int CH = (NT + 255) / 256;  // 7
  int lo = t * CH, hi = min(lo + CH, NT);
  int s = 0;
  for (int i = lo; i < hi; i++) s += tcnt[i];
  ps[t] = s;
  __syncthreads();
  for (int off = 1; off < 256; off <<= 1) {
    int v = ps[t];
    int u = (t >= off) ? ps[t - off] : 0;
    __syncthreads();
    ps[t] = v + u;
    __syncthreads();
  }
  int base = (t == 0) ? 0 : ps[t - 1];
  for (int i = lo; i < hi; i++) {
    tstart[i] = base;
    gcursor[i] = base;
    base += tcnt[i];
  }
  if (t == 0) tstart[NT] = N_EDGES;
}

// ---------------- CSR stage 3: scatter into tile buckets (local writes) -----
__global__ __launch_bounds__(256) void reorder2_kernel(const int* __restrict__ ei,
                                                       int* __restrict__ gcursor,
                                                       int* __restrict__ epack) {
  __shared__ int hist[NT];
  int t = threadIdx.x;
  for (int i = t; i < NT; i += 256) hist[i] = 0;
  __syncthreads();
  int base = blockIdx.x * EB;
#pragma unroll 4
  for (int i = 0; i < EB / 256; i++) {
    int e = base + i * 256 + t;
    if (e < N_EDGES) atomicAdd(&hist[ei[N_EDGES + e] >> 6], 1);
  }
  __syncthreads();
  for (int i = t; i < NT; i += 256) {
    int h = hist[i];
    if (h) hist[i] = atomicAdd(&gcursor[i], h);
  }
  __syncthreads();
#pragma unroll 4
  for (int i = 0; i < EB / 256; i++) {
    int e = base + i * 256 + t;
    if (e < N_EDGES) {
      int d = ei[N_EDGES + e];
      int s = ei[e];
      int pos = atomicAdd(&hist[d >> 6], 1);
      epack[pos] = (s << 6) | (d & 63);
    }
  }
}

// ---------------- CSR stage 4: per-tile counting sort -> row CSR ------------
__global__ __launch_bounds__(256) void row_sort_kernel(const int* __restrict__ tstart,
                                                       const int* __restrict__ epack,
                                                       int* __restrict__ starts,
                                                       int* __restrict__ srcs) {
  __shared__ int cnt[64];
  __shared__ int rbase[65];
  __shared__ int rofs[64];
  int t = threadIdx.x, b = blockIdx.x;
  int ts = tstart[b], te = tstart[b + 1];
  if (t < 64) cnt[t] = 0;
  __syncthreads();
  for (int i = ts + t; i < te; i += 256) atomicAdd(&cnt[epack[i] & 63], 1);
  __syncthreads();
  if (t == 0) {
    int a = 0;
    for (int r = 0; r < 64; r++) { rbase[r] = a; a += cnt[r]; }
    rbase[64] = a;
  }
  __syncthreads();
  if (t < 64) rofs[t] = ts + rbase[t];
  if (t <= 64) {
    int gr = b * 64 + t;
    if (gr <= N_NODES) starts[gr] = ts + rbase[t];
  }
  __syncthreads();
  for (int i = ts + t; i < te; i += 256) {
    int p = epack[i];
    int pos = atomicAdd(&rofs[p & 63], 1);
    srcs[pos] = p >> 6;
  }
}

// ---------------- gather (+ optional fused BN-relu on inputs) ---------------
// z[row] = h(row) + sum_{CSR[row]} h(src),  h(v) = BN ? relu(a*v+b) : v
// 2 edges per wave-iteration: lanes 0-31 take edge j, lanes 32-63 edge j+1;
// each lane loads 8B (C=128: bf16x4 / 4 feats) -> half the loads + VALU of the
// 1-edge/iter version. Final __shfl_xor(32) merges the halves.
template <int C, bool BN>
__global__ __launch_bounds__(256) void gather_kernel(const __bf16* __restrict__ h,
                                                     const float* __restrict__ bnab,
                                                     const int* __restrict__ starts,
                                                     const int* __restrict__ srcs,
                                                     __bf16* __restrict__ z) {
  const int lane = threadIdx.x & 63;
  const int half = lane >> 5;
  const int fl = lane & 31;
  const int row = blockIdx.x * 4 + (threadIdx.x >> 6);
  if (row >= N_NODES) return;
  int e0 = starts[row], e1 = starts[row + 1];
  int deg = e1 - e0;
  int idxv = srcs[min(e0 + lane, N_EDGES - 1)];
  int dcap = min(deg, 64);

  if constexpr (C == 128) {
    f32x4 a4, b4;
    if constexpr (BN) {
      a4 = *(const f32x4*)(bnab + fl * 4);
      b4 = *(const f32x4*)(bnab + HID + fl * 4);
    }
#define ACC4(vv, ss)                                                   \
    do {                                                               \
      if constexpr (BN) {                                              \
        ss[0] += fmaxf(fmaf(a4[0], (float)(vv)[0], b4[0]), 0.f);       \
        ss[1] += fmaxf(fmaf(a4[1], (float)(vv)[1], b4[1]), 0.f);       \
        ss[2] += fmaxf(fmaf(a4[2], (float)(vv)[2], b4[2]), 0.f);       \
        ss[3] += fmaxf(fmaf(a4[3], (float)(vv)[3], b4[3]), 0.f);       \
      } else {                                                         \
        ss[0] += (float)(vv)[0]; ss[1] += (float)(vv)[1];              \
        ss[2] += (float)(vv)[2]; ss[3] += (float)(vv)[3];              \
      }                                                                \
    } while (0)
    f32x4 sa[4] = {};
    int j = 0;
    for (; j + 15 < dcap; j += 16) {  // 16 edges: 8 pair-loads in flight
      int idx[8];
#pragma unroll
      for (int k = 0; k < 8; k++) {
        int p = __builtin_amdgcn_readlane(idxv, j + 2 * k);
        int q = __builtin_amdgcn_readlane(idxv, j + 2 * k + 1);
        idx[k] = half ? q : p;
      }
      bf16x4 vv[8];
#pragma unroll
      for (int k = 0; k < 8; k++)
        vv[k] = *(const bf16x4*)(h + (size_t)idx[k] * 128 + fl * 4);
#pragma unroll
      for (int k = 0; k < 8; k++) ACC4(vv[k], sa[k & 3]);
    }
    for (; j + 1 < dcap; j += 2) {  // pair tail
      int p = __builtin_amdgcn_readlane(idxv, j);
      int q = __builtin_amdgcn_readlane(idxv, j + 1);
      int ik = half ? q : p;
      bf16x4 vv = *(const bf16x4*)(h + (size_t)ik * 128 + fl * 4);
      ACC4(vv, sa[0]);
    }
    if (j < dcap) {  // single leftover edge: low half only
      int p = __builtin_amdgcn_readlane(idxv, j);
      bf16x4 vv = *(const bf16x4*)(h + (size_t)p * 128 + fl * 4);
      if (half == 0) ACC4(vv, sa[0]);
    }
    for (int e = e0 + 64; e + 1 < e1; e += 2) {  // overflow (deg > 64), paired
      int ik = srcs[e + half];
      bf16x4 vv = *(const bf16x4*)(h + (size_t)ik * 128 + fl * 4);
      ACC4(vv, sa[1]);
    }
    if (deg > 64 && ((deg - 64) & 1)) {  // odd overflow leftover
      int ik = srcs[e1 - 1];
      bf16x4 vv = *(const bf16x4*)(h + (size_t)ik * 128 + fl * 4);
      if (half == 0) ACC4(vv, sa[1]);
    }
    f32x4 tot = (sa[0] + sa[1]) + (sa[2] + sa[3]);
#pragma unroll
    for (int i = 0; i < 4; i++) tot[i] += __shfl_xor(tot[i], 32);
    if (half == 0) {
      bf16x4 sv = *(const bf16x4*)(h + (size_t)row * 128 + fl * 4);
      ACC4(sv, tot);
      bf16x4 o = {(__bf16)tot[0], (__bf16)tot[1], (__bf16)tot[2], (__bf16)tot[3]};
      *(bf16x4*)(z + (size_t)row * 128 + fl * 4) = o;
    }
#undef ACC4
  } else {  // C == 64 (layer 0, BN=false): bf16x2 per lane, 2 edges per iter
    float2 sa[4] = {};
#define ACC2(vv, ss)                                                   \
    do {                                                               \
      ss.x += (float)(vv)[0];                                          \
      ss.y += (float)(vv)[1];                                          \
    } while (0)
    int j = 0;
    for (; j + 15 < dcap; j += 16) {
      int idx[8];
#pragma unroll
      for (int k = 0; k < 8; k++) {
        int p = __builtin_amdgcn_readlane(idxv, j + 2 * k);
        int q = __builtin_amdgcn_readlane(idxv, j + 2 * k + 1);
        idx[k] = half ? q : p;
      }
      bf16x2 vv[8];
#pragma unroll
      for (int k = 0; k < 8; k++)
        vv[k] = *(const bf16x2*)(h + (size_t)idx[k] * 64 + fl * 2);
#pragma unroll
      for (int k = 0; k < 8; k++) ACC2(vv[k], sa[k & 3]);
    }
    for (; j + 1 < dcap; j += 2) {
      int p = __builtin_amdgcn_readlane(idxv, j);
      int q = __builtin_amdgcn_readlane(idxv, j + 1);
      int ik = half ? q : p;
      bf16x2 vv = *(const bf16x2*)(h + (size_t)ik * 64 + fl * 2);
      ACC2(vv, sa[0]);
    }
    if (j < dcap) {
      int p = __builtin_amdgcn_readlane(idxv, j);
      bf16x2 vv = *(const bf16x2*)(h + (size_t)p * 64 + fl * 2);
      if (half == 0) ACC2(vv, sa[0]);
    }
    for (int e = e0 + 64; e + 1 < e1; e += 2) {
      int ik = srcs[e + half];
      bf16x2 vv = *(const bf16x2*)(h + (size_t)ik * 64 + fl * 2);
      ACC2(vv, sa[1]);
    }
    if (deg > 64 && ((deg - 64) & 1)) {
      int ik = srcs[e1 - 1];
      bf16x2 vv = *(const bf16x2*)(h + (size_t)ik * 64 + fl * 2);
      if (half == 0) ACC2(vv, sa[1]);
    }
    float tx = (sa[0].x + sa[1].x) + (sa[2].x + sa[3].x);
    float ty = (sa[0].y + sa[1].y) + (sa[2].y + sa[3].y);
    tx += __shfl_xor(tx, 32);
    ty += __shfl_xor(ty, 32);
    if (half == 0) {
      bf16x2 sv = *(const bf16x2*)(h + (size_t)row * 64 + fl * 2);
      tx += (float)sv[0];
      ty += (float)sv[1];
      bf16x2 o = {(__bf16)tx, (__bf16)ty};
      *(bf16x2*)(z + (size_t)row * 64 + fl * 2) = o;
    }
#undef ACC2
  }
}

// ---------------- barrier-free MLP: u = relu(z@W1+b1)@W2+b2 + BN partials ---
template <int CIN>
__global__ __launch_bounds__(256) void mlp_kernel(
    const __bf16* __restrict__ z, const __bf16* __restrict__ w1t,
    const float* __restrict__ b1, const __bf16* __restrict__ w2t,
    const float* __restrict__ b2, __bf16* __restrict__ u,
    float* __restrict__ part) {
  constexpr int TS = HID + 8;  // 136 row stride
  __shared__ __align__(16) __bf16 sm[64 * TS];  // 17408 B

  const int t = threadIdx.x;
  const int wave = t >> 6;
  const int lane = t & 63;
  const int l16 = lane & 15;
  const int quad = lane >> 4;
  const int rowbase = blockIdx.x * 64;
  const int nvalid = min(64, N_NODES - rowbase);
  const int arow = min(rowbase + wave * 16 + l16, N_NODES - 1);  // clamp OOB

  const f32x4 zero4 = {0.f, 0.f, 0.f, 0.f};
  f32x4 acc[8];

  // Phase B: t1 = relu(z @ W1 + b1) -> own LDS rows
  {
    bf16x8 af[CIN / 32];
    const __bf16* ap = z + (size_t)arow * CIN + quad * 8;
#pragma unroll
    for (int ks = 0; ks < CIN / 32; ks++) af[ks] = *(const bf16x8*)(ap + ks * 32);
#pragma unroll
    for (int ct = 0; ct < 8; ct++) acc[ct] = zero4;
#pragma unroll
    for (int ks = 0; ks < CIN / 32; ks++) {
#pragma unroll
      for (int ct = 0; ct < 8; ct++) {
        bf16x8 bfr = *(const bf16x8*)(w1t + (ct * 16 + l16) * CIN + ks * 32 + quad * 8);
        acc[ct] = __builtin_amdgcn_mfma_f32_16x16x32_bf16(af[ks], bfr, acc[ct], 0, 0, 0);
      }
    }
#pragma unroll
    for (int ct = 0; ct < 8; ct++) {
      int col = ct * 16 + l16;
      float bias = b1[col];
#pragma unroll
      for (int r = 0; r < 4; r++) {
        float v = acc[ct][r] + bias;
        sm[(wave * 16 + quad * 4 + r) * TS + col] = (__bf16)(v > 0.f ? v : 0.f);
      }
    }
  }

  // Phase C: u = t1 @ W2 + b2 -> own LDS rows (bf16)
  {
#pragma unroll
    for (int ct = 0; ct < 8; ct++) acc[ct] = zero4;
    const __bf16* arowp = sm + (wave * 16 + l16) * TS + quad * 8;
#pragma unroll
    for (int ks = 0; ks < HID / 32; ks++) {
      bf16x8 af = *(const bf16x8*)(arowp + ks * 32);
#pragma unroll
      for (int ct = 0; ct < 8; ct++) {
        bf16x8 bfr = *(const bf16x8*)(w2t + (ct * 16 + l16) * HID + ks * 32 + quad * 8);
        acc[ct] = __builtin_amdgcn_mfma_f32_16x16x32_bf16(af, bfr, acc[ct], 0, 0, 0);
      }
    }
#pragma unroll
    for (int ct = 0; ct < 8; ct++) {
      int col = ct * 16 + l16;
      float bias = b2[col];
#pragma unroll
      for (int r = 0; r < 4; r++) {
        sm[(wave * 16 + quad * 4 + r) * TS + col] = (__bf16)(acc[ct][r] + bias);
      }
    }
  }
  __syncthreads();  // the only barrier: tile complete

  // coalesced bf16 global store of u + per-block BN partials (no atomics)
  for (int f = t; f < 64 * 16; f += 256) {
    int r = f >> 4, c8 = f & 15;
    if (r < nvalid) {
      bf16x8 v = *(const bf16x8*)(sm + r * TS + c8 * 8);
      *(bf16x8*)(u + (size_t)(rowbase + r) * HID + c8 * 8) = v;
    }
  }
  if (t < HID) {
    float s = 0.f, sq = 0.f;
    for (int r = 0; r < nvalid; r++) {
      float v = (float)sm[r * TS + t];
      s += v;
      sq += v * v;
    }
    part[(size_t)blockIdx.x * 256 + t] = s;
    part[(size_t)blockIdx.x * 256 + HID + t] = sq;
  }
}

// ---------------- BN stats reduce + finalize (one block per column) ---------
__global__ __launch_bounds__(256) void bn_stats_kernel(const float* __restrict__ part,
                                                       const float* __restrict__ gamma,
                                                       const float* __restrict__ beta,
                                                       float* __restrict__ bnab) {
  __shared__ float ss[256], qq[256];
  int c = blockIdx.x;  // column 0..127
  int t = threadIdx.x;
  float s = 0.f, q = 0.f;
  for (int b = t; b < MB; b += 256) {
    s += part[(size_t)b * 256 + c];
    q += part[(size_t)b * 256 + HID + c];
  }
  ss[t] = s; qq[t] = q;
  __syncthreads();
  for (int off = 128; off > 0; off >>= 1) {
    if (t < off) { ss[t] += ss[t + off]; qq[t] += qq[t + off]; }
    __syncthreads();
  }
  if (t == 0) {
    const float invN = 1.f / (float)N_NODES;
    float mean = ss[0] * invN;
    float var = qq[0] * invN - mean * mean;
    float a = gamma[c] * rsqrtf(var + BN_EPS);
    bnab[c] = a;
    bnab[HID + c] = beta[c] - mean * a;
  }
}

// ---------------- BN apply + mean-pool accumulate (layer 2, bf16 in) --------
__global__ __launch_bounds__(128) void bn_apply_pool_kernel(const __bf16* __restrict__ u,
                                                            const float* __restrict__ bnab,
                                                            const int* __restrict__ batch,
                                                            float* __restrict__ pool) {
  int c = threadIdx.x;  // feature column
  int r0 = blockIdx.x * 64;
  if (r0 >= N_NODES) return;
  int rend = min(r0 + 64, N_NODES);
  float a = bnab[c], b = bnab[HID + c];
  float accv = 0.f;
  int curg = -1;
  for (int r = r0; r < rend; r++) {
    int g = batch[r];
    if (g != curg) {
      if (curg >= 0) atomicAdd(&pool[curg * HID + c], accv);
      curg = g;
      accv = 0.f;
    }
    float v = (float)u[(size_t)r * HID + c];
    v = v * a + b;
    accv += (v > 0.f ? v : 0.f);
  }
  if (curg >= 0) atomicAdd(&pool[curg * HID + c], accv);
}

// ---------------- hg = pool/cnt; out = hg @ proj_w + proj_b -----------------
__global__ __launch_bounds__(128) void pool_proj_kernel(const float* __restrict__ pool,
                                                        const int* __restrict__ counts,
                                                        const float* __restrict__ pw,
                                                        const float* __restrict__ pb,
                                                        float* __restrict__ out) {
  int g = blockIdx.x;
  int c = threadIdx.x;
  __shared__ float hg[HID];
  float cnt = (float)max(counts[g], 1);
  hg[c] = pool[g * HID + c] / cnt;
  __syncthreads();
  float acc = pb[c];
#pragma unroll 8
  for (int k = 0; k < HID; k++) acc += hg[k] * pw[k * HID + c];
  out[g * HID + c] = acc;
}

// ============================================================================
extern "C" void kernel_launch(void* const* d_in, const int* in_sizes, int n_in,
                              void* d_out, int out_size, void* d_ws, size_t ws_size,
                              hipStream_t stream) {
  (void)in_sizes; (void)n_in; (void)out_size; (void)ws_size;
  const float* x = (const float*)d_in[0];
  const int* ei = (const int*)d_in[1];
  const int* batch = (const int*)d_in[2];
  const float* w1[3] = {(const float*)d_in[3], (const float*)d_in[9], (const float*)d_in[15]};
  const float* b1[3] = {(const float*)d_in[4], (const float*)d_in[10], (const float*)d_in[16]};
  const float* w2[3] = {(const float*)d_in[5], (const float*)d_in[11], (const float*)d_in[17]};
  const float* b2[3] = {(const float*)d_in[6], (const float*)d_in[12], (const float*)d_in[18]};
  const float* gm[3] = {(const float*)d_in[7], (const float*)d_in[13], (const float*)d_in[19]};
  const float* bt[3] = {(const float*)d_in[8], (const float*)d_in[14], (const float*)d_in[20]};
  const float* pw = (const float*)d_in[21];
  const float* pb = (const float*)d_in[22];
  float* out = (float*)d_out;

  // workspace carve
  char* ws = (char*)d_ws;
  __bf16* bufA = (__bf16*)ws;        ws += (size_t)N_NODES * HID * 2;   // 25.6 MB
  __bf16* bufB = (__bf16*)ws;        ws += (size_t)N_NODES * HID * 2;   // 25.6 MB
  __bf16* bufC = (__bf16*)ws;        ws += (size_t)N_NODES * HID * 2;   // 25.6 MB (z scratch)
  __bf16* z0 = (__bf16*)ws;          ws += (size_t)N_NODES * 64 * 2;    // 12.8 MB (layer-0 z)
  __bf16* xb = (__bf16*)ws;          ws += (size_t)N_NODES * 64 * 2;    // 12.8 MB
  int* srcs = (int*)ws;              ws += (size_t)N_EDGES * 4;         // 6.4 MB
  int* epack = (int*)ws;             ws += (size_t)N_EDGES * 4;         // 6.4 MB
  int* starts = (int*)ws;            ws += (size_t)(N_NODES + 1) * 4;
  int* tcnt = (int*)ws;              ws += NT * 4;
  int* tstart = (int*)ws;            ws += (NT + 1) * 4;
  int* gcursor = (int*)ws;           ws += NT * 4;
  ws = (char*)(((uintptr_t)ws + 63) & ~(uintptr_t)63);
  float* part = (float*)ws;          ws += (size_t)MB * 256 * 4;        // 1.6 MB
  __bf16* wt_all = (__bf16*)ws;      ws += 90112 * 2;
  ws = (char*)(((uintptr_t)ws + 63) & ~(uintptr_t)63);
  float* bnab = (float*)ws;          ws += 256 * 4;
  float* pool = (float*)ws;          ws += N_GRAPHS * HID * 4;          // contiguous with counts
  int* counts = (int*)ws;            ws += N_GRAPHS * 4;

  __bf16* w1t0 = wt_all;
  __bf16* w2t0 = wt_all + 8192;
  __bf16* w1t1 = wt_all + 24576;
  __bf16* w2t1 = wt_all + 40960;
  __bf16* w1t2 = wt_all + 57344;
  __bf16* w2t2 = wt_all + 73728;

  const int gat_blocks = (N_NODES + 3) / 4;  // 25000

  // zero pool + counts (contiguous) FIRST (setup_kernel's count needs it)
  hipMemsetAsync(pool, 0, (size_t)N_GRAPHS * HID * 4 + N_GRAPHS * 4, stream);
  hipMemsetAsync(tcnt, 0, NT * 4, stream);

  // fused setup: x->bf16 (6250 blocks) + weight prep (352) + counts (7)
  setup_kernel<<<6609, 256, 0, stream>>>(x, xb, w1[0], w2[0], w1[1], w2[1],
                                         w1[2], w2[2], wt_all, batch, counts);

  // CSR build: tile hist -> tile scan -> tile-bucket scatter -> per-tile sort
  tile_hist_kernel<<<RB, 256, 0, stream>>>(ei, tcnt);
  tile_scan_kernel<<<1, 256, 0, stream>>>(tcnt, tstart, gcursor);
  reorder2_kernel<<<RB, 256, 0, stream>>>(ei, gcursor, epack);
  row_sort_kernel<<<NT, 256, 0, stream>>>(tstart, epack, starts, srcs);

  // layer 0: gather(xb) -> z0; barrier-free mlp64 -> bufA (u0)
  gather_kernel<64, false><<<gat_blocks, 256, 0, stream>>>(xb, nullptr, starts, srcs, z0);
  mlp_kernel<64><<<MB, 256, 0, stream>>>(z0, w1t0, b1[0], w2t0, b2[0], bufA, part);
  bn_stats_kernel<<<HID, 256, 0, stream>>>(part, gm[0], bt[0], bnab);

  // layer 1: BN-relu-gather(u0) -> bufC; mlp -> bufB (u1)
  gather_kernel<128, true><<<gat_blocks, 256, 0, stream>>>(bufA, bnab, starts, srcs, bufC);
  mlp_kernel<128><<<MB, 256, 0, stream>>>(bufC, w1t1, b1[1], w2t1, b2[1], bufB, part);
  bn_stats_kernel<<<HID, 256, 0, stream>>>(part, gm[1], bt[1], bnab);

  // layer 2: BN-relu-gather(u1) -> bufC; mlp -> bufA (u2)
  gather_kernel<128, true><<<gat_blocks, 256, 0, stream>>>(bufB, bnab, starts, srcs, bufC);
  mlp_kernel<128><<<MB, 256, 0, stream>>>(bufC, w1t2, b1[2], w2t2, b2[2], bufA, part);
  bn_stats_kernel<<<HID, 256, 0, stream>>>(part, gm[2], bt[2], bnab);

  bn_apply_pool_kernel<<<MB, 128, 0, stream>>>(bufA, bnab, batch, pool);

  pool_proj_kernel<<<N_GRAPHS, 128, 0, stream>>>(pool, counts, pw, pb, out);
}

// Round 5
// 593.195 us; speedup vs baseline: 1.0220x; 1.0220x over previous
//
#include <hip/hip_runtime.h>

#define N_NODES 100000
#define N_EDGES 1600000
#define N_GRAPHS 256
#define HID 128
#define BN_EPS 1e-5f

#define NT 1563        // ceil(N_NODES/64) tile buckets
#define EB 4096        // edges per reorder block
#define RB 391         // ceil(N_EDGES/EB)
#define MB 1563        // mlp blocks

typedef __bf16 bf16x8 __attribute__((ext_vector_type(8)));
typedef __bf16 bf16x4 __attribute__((ext_vector_type(4)));
typedef __bf16 bf16x2 __attribute__((ext_vector_type(2)));
typedef float f32x4 __attribute__((ext_vector_type(4)));

// ---------------- fused setup: x->bf16, weight prep, per-graph counts -------
__global__ __launch_bounds__(256) void setup_kernel(
    const float* __restrict__ x, __bf16* __restrict__ xb,
    const float* __restrict__ wa, const float* __restrict__ wb,
    const float* __restrict__ wc, const float* __restrict__ wd,
    const float* __restrict__ we, const float* __restrict__ wf,
    __bf16* __restrict__ wt,
    const int* __restrict__ batch, int* __restrict__ counts) {
  int b = blockIdx.x;
  if (b < 6250) {  // x convert: chunks of 4 floats
    int idx = b * 256 + threadIdx.x;
    if (idx >= N_NODES * 16) return;
    f32x4 v = ((const f32x4*)x)[idx];
    bf16x4 o = {(__bf16)v[0], (__bf16)v[1], (__bf16)v[2], (__bf16)v[3]};
    ((bf16x4*)xb)[idx] = o;
  } else if (b < 6250 + 352) {  // weight prep
    int idx = (b - 6250) * 256 + threadIdx.x;
    if (idx >= 90112) return;
    const float* w;
    int K, local;
    if (idx < 8192) { w = wa; K = 64; local = idx; }
    else {
      int s = (idx - 8192) / 16384;
      local = (idx - 8192) - s * 16384;
      K = 128;
      w = (s == 0) ? wb : (s == 1) ? wc : (s == 2) ? wd : (s == 3) ? we : wf;
    }
    int n = local / K, k = local - n * K;
    wt[idx] = (__bf16)w[k * 128 + n];
  } else {  // per-graph node counts (batch is sorted)
    int t = (b - 6602) * 256 + threadIdx.x;
    int r0 = t * 64;
    if (r0 >= N_NODES) return;
    int rend = min(r0 + 64, N_NODES);
    int curg = batch[r0], cnt = 0;
    for (int r = r0; r < rend; r++) {
      int g = batch[r];
      if (g != curg) {
        atomicAdd(&counts[curg], cnt);
        curg = g;
        cnt = 1;
      } else {
        cnt++;
      }
    }
    atomicAdd(&counts[curg], cnt);
  }
}

// ---------------- CSR stage 1: tile-bucket histogram (LDS-staged) -----------
__global__ __launch_bounds__(256) void tile_hist_kernel(const int* __restrict__ ei,
                                                        int* __restrict__ tcnt) {
  __shared__ int hist[NT];
  int t = threadIdx.x;
  for (int i = t; i < NT; i += 256) hist[i] = 0;
  __syncthreads();
  int base = blockIdx.x * EB;
#pragma unroll 4
  for (int i = 0; i < EB / 256; i++) {
    int e = base + i * 256 + t;
    if (e < N_EDGES) atomicAdd(&hist[ei[N_EDGES + e] >> 6], 1);
  }
  __syncthreads();
  for (int i = t; i < NT; i += 256) {
    int h = hist[i];
    if (h) atomicAdd(&tcnt[i], h);
  }
}

// ---------------- CSR stage 2: scan 1563 tile counts ------------------------
__global__ __launch_bounds__(256) void tile_scan_kernel(const int* __restrict__ tcnt,
                                                        int* __restrict__ tstart,
                                                        int* __restrict__ gcursor) {
  __shared__ int ps[256];
  int t = threadIdx.x;
  const int CH = (NT + 255) / 256;  // 7
  int lo = t * CH, hi = min(lo + CH, NT);
  int s = 0;
  for (int i = lo; i < hi; i++) s += tcnt[i];
  ps[t] = s;
  __syncthreads();
  for (int off = 1; off < 256; off <<= 1) {
    int v = ps[t];
    int u = (t >= off) ? ps[t - off] : 0;
    __syncthreads();
    ps[t] = v + u;
    __syncthreads();
  }
  int base = (t == 0) ? 0 : ps[t - 1];
  for (int i = lo; i < hi; i++) {
    tstart[i] = base;
    gcursor[i] = base;
    base += tcnt[i];
  }
  if (t == 0) tstart[NT] = N_EDGES;
}

// ---------------- CSR stage 3: scatter into tile buckets (local writes) -----
__global__ __launch_bounds__(256) void reorder2_kernel(const int* __restrict__ ei,
                                                       int* __restrict__ gcursor,
                                                       int* __restrict__ epack) {
  __shared__ int hist[NT];
  int t = threadIdx.x;
  for (int i = t; i < NT; i += 256) hist[i] = 0;
  __syncthreads();
  int base = blockIdx.x * EB;
#pragma unroll 4
  for (int i = 0; i < EB / 256; i++) {
    int e = base + i * 256 + t;
    if (e < N_EDGES) atomicAdd(&hist[ei[N_EDGES + e] >> 6], 1);
  }
  __syncthreads();
  for (int i = t; i < NT; i += 256) {
    int h = hist[i];
    if (h) hist[i] = atomicAdd(&gcursor[i], h);
  }
  __syncthreads();
#pragma unroll 4
  for (int i = 0; i < EB / 256; i++) {
    int e = base + i * 256 + t;
    if (e < N_EDGES) {
      int d = ei[N_EDGES + e];
      int s = ei[e];
      int pos = atomicAdd(&hist[d >> 6], 1);
      epack[pos] = (s << 6) | (d & 63);
    }
  }
}

// ---------------- CSR stage 4: per-tile counting sort -> row CSR ------------
__global__ __launch_bounds__(256) void row_sort_kernel(const int* __restrict__ tstart,
                                                       const int* __restrict__ epack,
                                                       int* __restrict__ starts,
                                                       int* __restrict__ srcs) {
  __shared__ int cnt[64];
  __shared__ int rbase[65];
  __shared__ int rofs[64];
  int t = threadIdx.x, b = blockIdx.x;
  int ts = tstart[b], te = tstart[b + 1];
  if (t < 64) cnt[t] = 0;
  __syncthreads();
  for (int i = ts + t; i < te; i += 256) atomicAdd(&cnt[epack[i] & 63], 1);
  __syncthreads();
  if (t == 0) {
    int a = 0;
    for (int r = 0; r < 64; r++) { rbase[r] = a; a += cnt[r]; }
    rbase[64] = a;
  }
  __syncthreads();
  if (t < 64) rofs[t] = ts + rbase[t];
  if (t <= 64) {
    int gr = b * 64 + t;
    if (gr <= N_NODES) starts[gr] = ts + rbase[t];
  }
  __syncthreads();
  for (int i = ts + t; i < te; i += 256) {
    int p = epack[i];
    int pos = atomicAdd(&rofs[p & 63], 1);
    srcs[pos] = p >> 6;
  }
}

// ---------------- gather (+ optional fused BN-relu on inputs) ---------------
// z[row] = h(row) + sum_{CSR[row]} h(src),  h(v) = BN ? relu(a*v+b) : v
// SCALAR-PATH edge loop: row is forced uniform via readfirstlane, so the edge
// list (srcs[e]) compiles to s_load and the h-row base to SGPR arithmetic.
// Per-edge VALU is just the accumulate (cvt+add / cvt+fma+max); addressing
// rides the scalar pipe. 1 row per wave, 4 rows per block -> 25000 blocks.
template <int C, bool BN>
__global__ __launch_bounds__(256) void gather_kernel(const __bf16* __restrict__ h,
                                                     const float* __restrict__ bnab,
                                                     const int* __restrict__ starts,
                                                     const int* __restrict__ srcs,
                                                     __bf16* __restrict__ z) {
  const int lane = threadIdx.x & 63;
  const int row = __builtin_amdgcn_readfirstlane(blockIdx.x * 4 + (threadIdx.x >> 6));
  const int e0 = starts[row], e1 = starts[row + 1];

  if constexpr (C == 128) {
    float a0 = 0.f, a1 = 0.f, b0 = 0.f, b1 = 0.f;
    if constexpr (BN) {
      a0 = bnab[lane * 2];
      a1 = bnab[lane * 2 + 1];
      b0 = bnab[HID + lane * 2];
      b1 = bnab[HID + lane * 2 + 1];
    }
#define ACCBN(vv, ss)                                                  \
    do {                                                               \
      if constexpr (BN) {                                              \
        ss.x += fmaxf(fmaf(a0, (float)(vv)[0], b0), 0.f);              \
        ss.y += fmaxf(fmaf(a1, (float)(vv)[1], b1), 0.f);              \
      } else {                                                         \
        ss.x += (float)(vv)[0];                                        \
        ss.y += (float)(vv)[1];                                        \
      }                                                                \
    } while (0)
    float2 s0 = {0.f, 0.f}, s1 = {0.f, 0.f}, s2 = {0.f, 0.f}, s3 = {0.f, 0.f};
    int e = e0;
    for (; e + 3 < e1; e += 4) {
      int i0 = srcs[e];      // uniform -> s_load
      int i1 = srcs[e + 1];
      int i2 = srcs[e + 2];
      int i3 = srcs[e + 3];
      bf16x2 v0 = *(const bf16x2*)(h + (size_t)i0 * 128 + lane * 2);
      bf16x2 v1 = *(const bf16x2*)(h + (size_t)i1 * 128 + lane * 2);
      bf16x2 v2 = *(const bf16x2*)(h + (size_t)i2 * 128 + lane * 2);
      bf16x2 v3 = *(const bf16x2*)(h + (size_t)i3 * 128 + lane * 2);
      ACCBN(v0, s0);
      ACCBN(v1, s1);
      ACCBN(v2, s2);
      ACCBN(v3, s3);
    }
    for (; e < e1; e++) {
      int i0 = srcs[e];
      bf16x2 vv = *(const bf16x2*)(h + (size_t)i0 * 128 + lane * 2);
      ACCBN(vv, s0);
    }
    bf16x2 sv = *(const bf16x2*)(h + (size_t)row * 128 + lane * 2);
    ACCBN(sv, s0);
    float tx = (s0.x + s1.x) + (s2.x + s3.x);
    float ty = (s0.y + s1.y) + (s2.y + s3.y);
    bf16x2 o = {(__bf16)tx, (__bf16)ty};
    *(bf16x2*)(z + (size_t)row * 128 + lane * 2) = o;
#undef ACCBN
  } else {  // C == 64 (layer 0, no BN): 1 bf16 per lane, scalar-path loop
    float s0 = 0.f, s1 = 0.f, s2 = 0.f, s3 = 0.f;
    int e = e0;
    for (; e + 3 < e1; e += 4) {
      int i0 = srcs[e];
      int i1 = srcs[e + 1];
      int i2 = srcs[e + 2];
      int i3 = srcs[e + 3];
      float v0 = (float)h[(size_t)i0 * 64 + lane];
      float v1 = (float)h[(size_t)i1 * 64 + lane];
      float v2 = (float)h[(size_t)i2 * 64 + lane];
      float v3 = (float)h[(size_t)i3 * 64 + lane];
      s0 += v0; s1 += v1; s2 += v2; s3 += v3;
    }
    for (; e < e1; e++) {
      int i0 = srcs[e];
      s0 += (float)h[(size_t)i0 * 64 + lane];
    }
    s0 += (float)h[(size_t)row * 64 + lane];
    float tot = (s0 + s1) + (s2 + s3);
    z[(size_t)row * 64 + lane] = (__bf16)tot;
  }
}

// ---------------- barrier-free MLP: u = relu(z@W1+b1)@W2+b2 + BN partials ---
template <int CIN>
__global__ __launch_bounds__(256) void mlp_kernel(
    const __bf16* __restrict__ z, const __bf16* __restrict__ w1t,
    const float* __restrict__ b1, const __bf16* __restrict__ w2t,
    const float* __restrict__ b2, __bf16* __restrict__ u,
    float* __restrict__ part) {
  constexpr int TS = HID + 8;  // 136 row stride
  __shared__ __align__(16) __bf16 sm[64 * TS];  // 17408 B

  const int t = threadIdx.x;
  const int wave = t >> 6;
  const int lane = t & 63;
  const int l16 = lane & 15;
  const int quad = lane >> 4;
  const int rowbase = blockIdx.x * 64;
  const int nvalid = min(64, N_NODES - rowbase);
  const int arow = min(rowbase + wave * 16 + l16, N_NODES - 1);  // clamp OOB

  const f32x4 zero4 = {0.f, 0.f, 0.f, 0.f};
  f32x4 acc[8];

  // Phase B: t1 = relu(z @ W1 + b1) -> own LDS rows
  {
    bf16x8 af[CIN / 32];
    const __bf16* ap = z + (size_t)arow * CIN + quad * 8;
#pragma unroll
    for (int ks = 0; ks < CIN / 32; ks++) af[ks] = *(const bf16x8*)(ap + ks * 32);
#pragma unroll
    for (int ct = 0; ct < 8; ct++) acc[ct] = zero4;
#pragma unroll
    for (int ks = 0; ks < CIN / 32; ks++) {
#pragma unroll
      for (int ct = 0; ct < 8; ct++) {
        bf16x8 bfr = *(const bf16x8*)(w1t + (ct * 16 + l16) * CIN + ks * 32 + quad * 8);
        acc[ct] = __builtin_amdgcn_mfma_f32_16x16x32_bf16(af[ks], bfr, acc[ct], 0, 0, 0);
      }
    }
#pragma unroll
    for (int ct = 0; ct < 8; ct++) {
      int col = ct * 16 + l16;
      float bias = b1[col];
#pragma unroll
      for (int r = 0; r < 4; r++) {
        float v = acc[ct][r] + bias;
        sm[(wave * 16 + quad * 4 + r) * TS + col] = (__bf16)(v > 0.f ? v : 0.f);
      }
    }
  }

  // Phase C: u = t1 @ W2 + b2 -> own LDS rows (bf16)
  {
#pragma unroll
    for (int ct = 0; ct < 8; ct++) acc[ct] = zero4;
    const __bf16* arowp = sm + (wave * 16 + l16) * TS + quad * 8;
#pragma unroll
    for (int ks = 0; ks < HID / 32; ks++) {
      bf16x8 af = *(const bf16x8*)(arowp + ks * 32);
#pragma unroll
      for (int ct = 0; ct < 8; ct++) {
        bf16x8 bfr = *(const bf16x8*)(w2t + (ct * 16 + l16) * HID + ks * 32 + quad * 8);
        acc[ct] = __builtin_amdgcn_mfma_f32_16x16x32_bf16(af, bfr, acc[ct], 0, 0, 0);
      }
    }
#pragma unroll
    for (int ct = 0; ct < 8; ct++) {
      int col = ct * 16 + l16;
      float bias = b2[col];
#pragma unroll
      for (int r = 0; r < 4; r++) {
        sm[(wave * 16 + quad * 4 + r) * TS + col] = (__bf16)(acc[ct][r] + bias);
      }
    }
  }
  __syncthreads();  // the only barrier: tile complete

  // coalesced bf16 global store of u + per-block BN partials (no atomics)
  for (int f = t; f < 64 * 16; f += 256) {
    int r = f >> 4, c8 = f & 15;
    if (r < nvalid) {
      bf16x8 v = *(const bf16x8*)(sm + r * TS + c8 * 8);
      *(bf16x8*)(u + (size_t)(rowbase + r) * HID + c8 * 8) = v;
    }
  }
  if (t < HID) {
    float s = 0.f, sq = 0.f;
    for (int r = 0; r < nvalid; r++) {
      float v = (float)sm[r * TS + t];
      s += v;
      sq += v * v;
    }
    part[(size_t)blockIdx.x * 256 + t] = s;
    part[(size_t)blockIdx.x * 256 + HID + t] = sq;
  }
}

// ---------------- BN stats reduce + finalize (one block per column) ---------
__global__ __launch_bounds__(256) void bn_stats_kernel(const float* __restrict__ part,
                                                       const float* __restrict__ gamma,
                                                       const float* __restrict__ beta,
                                                       float* __restrict__ bnab) {
  __shared__ float ss[256], qq[256];
  int c = blockIdx.x;  // column 0..127
  int t = threadIdx.x;
  float s = 0.f, q = 0.f;
  for (int b = t; b < MB; b += 256) {
    s += part[(size_t)b * 256 + c];
    q += part[(size_t)b * 256 + HID + c];
  }
  ss[t] = s; qq[t] = q;
  __syncthreads();
  for (int off = 128; off > 0; off >>= 1) {
    if (t < off) { ss[t] += ss[t + off]; qq[t] += qq[t + off]; }
    __syncthreads();
  }
  if (t == 0) {
    const float invN = 1.f / (float)N_NODES;
    float mean = ss[0] * invN;
    float var = qq[0] * invN - mean * mean;
    float a = gamma[c] * rsqrtf(var + BN_EPS);
    bnab[c] = a;
    bnab[HID + c] = beta[c] - mean * a;
  }
}

// ---------------- BN apply + mean-pool accumulate (layer 2, bf16 in) --------
__global__ __launch_bounds__(128) void bn_apply_pool_kernel(const __bf16* __restrict__ u,
                                                            const float* __restrict__ bnab,
                                                            const int* __restrict__ batch,
                                                            float* __restrict__ pool) {
  int c = threadIdx.x;  // feature column
  int r0 = blockIdx.x * 64;
  if (r0 >= N_NODES) return;
  int rend = min(r0 + 64, N_NODES);
  float a = bnab[c], b = bnab[HID + c];
  float accv = 0.f;
  int curg = -1;
  for (int r = r0; r < rend; r++) {
    int g = batch[r];
    if (g != curg) {
      if (curg >= 0) atomicAdd(&pool[curg * HID + c], accv);
      curg = g;
      accv = 0.f;
    }
    float v = (float)u[(size_t)r * HID + c];
    v = v * a + b;
    accv += (v > 0.f ? v : 0.f);
  }
  if (curg >= 0) atomicAdd(&pool[curg * HID + c], accv);
}

// ---------------- hg = pool/cnt; out = hg @ proj_w + proj_b -----------------
__global__ __launch_bounds__(128) void pool_proj_kernel(const float* __restrict__ pool,
                                                        const int* __restrict__ counts,
                                                        const float* __restrict__ pw,
                                                        const float* __restrict__ pb,
                                                        float* __restrict__ out) {
  int g = blockIdx.x;
  int c = threadIdx.x;
  __shared__ float hg[HID];
  float cnt = (float)max(counts[g], 1);
  hg[c] = pool[g * HID + c] / cnt;
  __syncthreads();
  float acc = pb[c];
#pragma unroll 8
  for (int k = 0; k < HID; k++) acc += hg[k] * pw[k * HID + c];
  out[g * HID + c] = acc;
}

// ============================================================================
extern "C" void kernel_launch(void* const* d_in, const int* in_sizes, int n_in,
                              void* d_out, int out_size, void* d_ws, size_t ws_size,
                              hipStream_t stream) {
  (void)in_sizes; (void)n_in; (void)out_size; (void)ws_size;
  const float* x = (const float*)d_in[0];
  const int* ei = (const int*)d_in[1];
  const int* batch = (const int*)d_in[2];
  const float* w1[3] = {(const float*)d_in[3], (const float*)d_in[9], (const float*)d_in[15]};
  const float* b1[3] = {(const float*)d_in[4], (const float*)d_in[10], (const float*)d_in[16]};
  const float* w2[3] = {(const float*)d_in[5], (const float*)d_in[11], (const float*)d_in[17]};
  const float* b2[3] = {(const float*)d_in[6], (const float*)d_in[12], (const float*)d_in[18]};
  const float* gm[3] = {(const float*)d_in[7], (const float*)d_in[13], (const float*)d_in[19]};
  const float* bt[3] = {(const float*)d_in[8], (const float*)d_in[14], (const float*)d_in[20]};
  const float* pw = (const float*)d_in[21];
  const float* pb = (const float*)d_in[22];
  float* out = (float*)d_out;

  // workspace carve
  char* ws = (char*)d_ws;
  __bf16* bufA = (__bf16*)ws;        ws += (size_t)N_NODES * HID * 2;   // 25.6 MB
  __bf16* bufB = (__bf16*)ws;        ws += (size_t)N_NODES * HID * 2;   // 25.6 MB
  __bf16* bufC = (__bf16*)ws;        ws += (size_t)N_NODES * HID * 2;   // 25.6 MB (z scratch)
  __bf16* z0 = (__bf16*)ws;          ws += (size_t)N_NODES * 64 * 2;    // 12.8 MB (layer-0 z)
  __bf16* xb = (__bf16*)ws;          ws += (size_t)N_NODES * 64 * 2;    // 12.8 MB
  int* srcs = (int*)ws;              ws += (size_t)N_EDGES * 4;         // 6.4 MB
  int* epack = (int*)ws;             ws += (size_t)N_EDGES * 4;         // 6.4 MB
  int* starts = (int*)ws;            ws += (size_t)(N_NODES + 1) * 4;
  int* tcnt = (int*)ws;              ws += NT * 4;
  int* tstart = (int*)ws;            ws += (NT + 1) * 4;
  int* gcursor = (int*)ws;           ws += NT * 4;
  ws = (char*)(((uintptr_t)ws + 63) & ~(uintptr_t)63);
  float* part = (float*)ws;          ws += (size_t)MB * 256 * 4;        // 1.6 MB
  __bf16* wt_all = (__bf16*)ws;      ws += 90112 * 2;
  ws = (char*)(((uintptr_t)ws + 63) & ~(uintptr_t)63);
  float* bnab = (float*)ws;          ws += 256 * 4;
  float* pool = (float*)ws;          ws += N_GRAPHS * HID * 4;          // contiguous with counts
  int* counts = (int*)ws;            ws += N_GRAPHS * 4;

  __bf16* w1t0 = wt_all;
  __bf16* w2t0 = wt_all + 8192;
  __bf16* w1t1 = wt_all + 24576;
  __bf16* w2t1 = wt_all + 40960;
  __bf16* w1t2 = wt_all + 57344;
  __bf16* w2t2 = wt_all + 73728;

  const int gat_blocks = (N_NODES + 3) / 4;  // 25000

  // zero pool + counts (contiguous) FIRST (setup_kernel's count needs it)
  hipMemsetAsync(pool, 0, (size_t)N_GRAPHS * HID * 4 + N_GRAPHS * 4, stream);
  hipMemsetAsync(tcnt, 0, NT * 4, stream);

  // fused setup: x->bf16 (6250 blocks) + weight prep (352) + counts (7)
  setup_kernel<<<6609, 256, 0, stream>>>(x, xb, w1[0], w2[0], w1[1], w2[1],
                                         w1[2], w2[2], wt_all, batch, counts);

  // CSR build: tile hist -> tile scan -> tile-bucket scatter -> per-tile sort
  tile_hist_kernel<<<RB, 256, 0, stream>>>(ei, tcnt);
  tile_scan_kernel<<<1, 256, 0, stream>>>(tcnt, tstart, gcursor);
  reorder2_kernel<<<RB, 256, 0, stream>>>(ei, gcursor, epack);
  row_sort_kernel<<<NT, 256, 0, stream>>>(tstart, epack, starts, srcs);

  // layer 0: gather(xb) -> z0; barrier-free mlp64 -> bufA (u0)
  gather_kernel<64, false><<<gat_blocks, 256, 0, stream>>>(xb, nullptr, starts, srcs, z0);
  mlp_kernel<64><<<MB, 256, 0, stream>>>(z0, w1t0, b1[0], w2t0, b2[0], bufA, part);
  bn_stats_kernel<<<HID, 256, 0, stream>>>(part, gm[0], bt[0], bnab);

  // layer 1: BN-relu-gather(u0) -> bufC; mlp -> bufB (u1)
  gather_kernel<128, true><<<gat_blocks, 256, 0, stream>>>(bufA, bnab, starts, srcs, bufC);
  mlp_kernel<128><<<MB, 256, 0, stream>>>(bufC, w1t1, b1[1], w2t1, b2[1], bufB, part);
  bn_stats_kernel<<<HID, 256, 0, stream>>>(part, gm[1], bt[1], bnab);

  // layer 2: BN-relu-gather(u1) -> bufC; mlp -> bufA (u2)
  gather_kernel<128, true><<<gat_blocks, 256, 0, stream>>>(bufB, bnab, starts, srcs, bufC);
  mlp_kernel<128><<<MB, 256, 0, stream>>>(bufC, w1t2, b1[2], w2t2, b2[2], bufA, part);
  bn_stats_kernel<<<HID, 256, 0, stream>>>(part, gm[2], bt[2], bnab);

  bn_apply_pool_kernel<<<MB, 128, 0, stream>>>(bufA, bnab, batch, pool);

  pool_proj_kernel<<<N_GRAPHS, 128, 0, stream>>>(pool, counts, pw, pb, out);
}